// Round 6
// baseline (154.881 us; speedup 1.0000x reference)
//
#include <hip/hip_runtime.h>
#include <math.h>

// Problem constants
#define Bb   2
#define Hh   64
#define Ww   160
#define DIMc 256
#define Nn   (Hh * Ww)                 // 10240 positions per batch
#define NPOS (Bb * Nn)                 // 20480 total positions
#define SCALEf 0.17677669529663687f    // 32^-0.5

typedef unsigned short u16;
typedef unsigned int   u32;
typedef __bf16 bf16x8 __attribute__((ext_vector_type(8)));
typedef float  f32x4  __attribute__((ext_vector_type(4)));

// fp32 -> bf16 round-to-nearest-even
__device__ __forceinline__ u16 f2bf(float f) {
    u32 u = __float_as_uint(f);
    u += 0x7fffu + ((u >> 16) & 1u);
    return (u16)(u >> 16);
}
__device__ __forceinline__ u32 pack2(float lo, float hi) {
    return (u32)f2bf(lo) | ((u32)f2bf(hi) << 16);
}
// packed bf16 pair -> floats (exact)
__device__ __forceinline__ float bflo(u32 u) { return __uint_as_float(u << 16); }
__device__ __forceinline__ float bfhi(u32 u) { return __uint_as_float(u & 0xffff0000u); }

// async global(16B) -> LDS direct staging (wave-uniform base + lane*16)
__device__ __forceinline__ void gload16(const void* g, void* l) {
    __builtin_amdgcn_global_load_lds(
        (const __attribute__((address_space(1))) unsigned int*)g,
        (__attribute__((address_space(3))) unsigned int*)l,
        16, 0, 0);
}

// ---------------------------------------------------------------------------
// prep_w: weights -> transposed bf16. Wt[wsel][n][k] = W[wsel][k][n]. (R0)
// ---------------------------------------------------------------------------
__global__ __launch_bounds__(256) void prep_w(const float* __restrict__ Wq,
                                              const float* __restrict__ Wk,
                                              const float* __restrict__ Wv,
                                              const float* __restrict__ Wp,
                                              u16* __restrict__ WtAll)
{
    int id = blockIdx.x * 256 + threadIdx.x;     // 0 .. 262143
    int wsel = id >> 16;
    int rem  = id & 65535;
    int kk = rem >> 8, nn = rem & 255;
    const float* W = (wsel == 0) ? Wq : (wsel == 1) ? Wk : (wsel == 2) ? Wv : Wp;
    WtAll[(size_t)wsel * 65536 + nn * 256 + kk] = f2bf(W[kk * 256 + nn]);
}

// ---------------------------------------------------------------------------
// QKV GEMM (R0-proven, best-measured): A fp32 loaded + packed bf16 in-reg,
// B bf16 via global_load_lds width=16. Natural output layout.
// ---------------------------------------------------------------------------
__global__ __launch_bounds__(256) void gemm_qkv(const float* __restrict__ x,
                                                const u16* __restrict__ WtAll,
                                                u16* __restrict__ q,
                                                u16* __restrict__ k,
                                                u16* __restrict__ v)
{
    __shared__ __align__(16) char smem[32768];
    u16* sA = (u16*)smem;             //  8 KB: 128 rows x 32 k
    u16* sB = (u16*)(smem + 8192);    //  8 KB: 128 cols x 32 k

    const int z = blockIdx.z;
    u16* Cb = (z == 0) ? q : (z == 1) ? k : v;
    const u16* Btg = WtAll + (size_t)z * 65536;

    const int t    = threadIdx.x;
    const int lane = t & 63;
    const int wv   = t >> 6;
    const int wm   = wv & 1;
    const int wn   = wv >> 1;
    const int m0   = blockIdx.y * 128;
    const int n0   = blockIdx.x * 128;

    const int r0  = t >> 2;
    const int kc0 = (t & 3) * 8;

    const int col  = lane & 15;
    const int quad = lane >> 4;

    f32x4 acc[4][4];
#pragma unroll
    for (int i = 0; i < 4; ++i)
#pragma unroll
        for (int j = 0; j < 4; ++j)
            acc[i][j] = (f32x4){0.f, 0.f, 0.f, 0.f};

    const u16* Bbase = Btg + (size_t)n0 * 256;
    char* ldsB0 = smem + 8192 + wv * 1024;
    char* ldsB1 = smem + 8192 + 4096 + wv * 1024;

    for (int k0 = 0; k0 < 256; k0 += 32) {
        const float* ap0 = x + (size_t)(m0 + r0) * 256 + k0 + kc0;
        const float* ap1 = x + (size_t)(m0 + 64 + r0) * 256 + k0 + kc0;
        float4 f0 = *(const float4*)ap0, f1 = *(const float4*)(ap0 + 4);
        float4 f2 = *(const float4*)ap1, f3 = *(const float4*)(ap1 + 4);
        uint4 a0, a1;
        a0.x = pack2(f0.x, f0.y); a0.y = pack2(f0.z, f0.w);
        a0.z = pack2(f1.x, f1.y); a0.w = pack2(f1.z, f1.w);
        a1.x = pack2(f2.x, f2.y); a1.y = pack2(f2.z, f2.w);
        a1.z = pack2(f3.x, f3.y); a1.w = pack2(f3.z, f3.w);

        __syncthreads();
        *(uint4*)(sA + r0 * 32 + kc0)        = a0;
        *(uint4*)(sA + (64 + r0) * 32 + kc0) = a1;
        gload16(Bbase + (size_t)r0        * 256 + k0 + kc0, ldsB0);
        gload16(Bbase + (size_t)(64 + r0) * 256 + k0 + kc0, ldsB1);
        __syncthreads();

        bf16x8 af[4], bfr[4];
#pragma unroll
        for (int mt = 0; mt < 4; ++mt)
            af[mt] = *(const bf16x8*)(sA + (wm * 64 + mt * 16 + col) * 32 + quad * 8);
#pragma unroll
        for (int nt = 0; nt < 4; ++nt)
            bfr[nt] = *(const bf16x8*)(sB + (wn * 64 + nt * 16 + col) * 32 + quad * 8);

#pragma unroll
        for (int mt = 0; mt < 4; ++mt)
#pragma unroll
            for (int nt = 0; nt < 4; ++nt)
                acc[mt][nt] = __builtin_amdgcn_mfma_f32_16x16x32_bf16(af[mt], bfr[nt], acc[mt][nt], 0, 0, 0);
    }

    __syncthreads();
    u16* sC = (u16*)smem;             // 128 x 128 bf16 = 32 KB
#pragma unroll
    for (int mt = 0; mt < 4; ++mt)
#pragma unroll
        for (int nt = 0; nt < 4; ++nt) {
            const int rw = wm * 64 + mt * 16 + quad * 4;
            const int cl = wn * 64 + nt * 16 + col;
#pragma unroll
            for (int rr = 0; rr < 4; ++rr)
                sC[(rw + rr) * 128 + cl] = f2bf(acc[mt][nt][rr]);
        }
    __syncthreads();
#pragma unroll
    for (int i = 0; i < 8; ++i) {
        int j   = i * 256 + t;
        int row = j >> 4;
        int off = (j & 15) * 8;
        *(uint4*)(Cb + (size_t)(m0 + row) * 256 + n0 + off) = *(const uint4*)(sC + row * 128 + off);
    }
}

// ---------------------------------------------------------------------------
// Attention: ONE WAVE per position. NEW lane mapping for coalesced K-reads:
//   hi = lane>>5, h = (lane>>2)&7, jj = lane&3.
// Each K-load instruction covers window slots a = 2i+hi: lanes 0..31 read
// row(2i) bytes 0..511 contiguous, lanes 32..63 read row(2i+1) (adjacent
// image column -> contiguous 1KB total) — 16 cache lines/instr vs 64 in the
// (h=lane&7, a0=lane>>3) mapping. Score for (a, head h) is reduced over the
// 4 jj-lanes with 2 shfl_xor; softmax over 16 a's = 8 in-register +
// shfl_xor(32). V-phase identical to R0 except the p-broadcast source lane.
// ---------------------------------------------------------------------------
__global__ __launch_bounds__(256) void attn_kernel(const u16* __restrict__ q,
                                                   const u16* __restrict__ k,
                                                   const u16* __restrict__ v,
                                                   const float* __restrict__ moff,
                                                   u16* __restrict__ ao)
{
    const int wv   = threadIdx.x >> 6;
    const int lane = threadIdx.x & 63;
    const int pos  = blockIdx.x * 4 + wv;
    const int rowbase = (pos >= Nn) ? Nn : 0;

    float2 mo = *(const float2*)(moff + (size_t)pos * 2);
    float ox = fminf(fmaxf(mo.x, 1.0f), (float)(Ww - 2) - 0.001f);
    float oy = fminf(fmaxf(mo.y, 1.0f), (float)(Hh - 2) - 0.001f);
    float mxf = floorf(ox), myf = floorf(oy);
    float fx = ox - mxf, fy = oy - myf;
    int imx = (int)mxf, imy = (int)myf;

    const int hi = lane >> 5;         // window-slot parity this lane scores
    const int h  = (lane >> 2) & 7;   // head this lane scores
    const int jj = lane & 3;          // 8-dim chunk within the head

    // Q chunk (head h, dims jj*8..jj*8+7): ONE 16B load (512B/pos, 8 lines)
    const uint4 q4 = *(const uint4*)(q + (size_t)pos * 256 + h * 32 + jj * 8);

    // K phase: 8 instructions, each 1KB contiguous (rows a=2i, 2i+1)
    float s[8];
#pragma unroll
    for (int i = 0; i < 8; ++i) {
        int a   = 2 * i + hi;
        int row = rowbase + (imy + (a >> 2) - 1) * Ww + imx + (a & 3) - 1;
        uint4 kw = *(const uint4*)(k + (size_t)row * 256 + h * 32 + jj * 8);
        float acc = bflo(q4.x) * bflo(kw.x) + bfhi(q4.x) * bfhi(kw.x)
                  + bflo(q4.y) * bflo(kw.y) + bfhi(q4.y) * bfhi(kw.y)
                  + bflo(q4.z) * bflo(kw.z) + bfhi(q4.z) * bfhi(kw.z)
                  + bflo(q4.w) * bflo(kw.w) + bfhi(q4.w) * bfhi(kw.w);
        acc += __shfl_xor(acc, 1);    // reduce over jj (tree)
        acc += __shfl_xor(acc, 2);
        s[i] = acc * SCALEf;          // s(a=2i+hi, head h), replicated x4 jj
    }

    // softmax over the 16 window slots for head h
    auto wc = [](int r, float f) { return r == 0 ? 1.f - f : (r == 3 ? f : 1.f); };
    float m = s[0];
#pragma unroll
    for (int i = 1; i < 8; ++i) m = fmaxf(m, s[i]);
    m = fmaxf(m, __shfl_xor(m, 32));  // combine hi=0 / hi=1 halves

    float p[8];
    float sum = 0.f;
#pragma unroll
    for (int i = 0; i < 8; ++i) {
        int a = 2 * i + hi;
        float bwv = wc(a >> 2, fy) * wc(a & 3, fx);
        p[i] = expf(s[i] - m) * bwv;
        sum += p[i];
    }
    sum += __shfl_xor(sum, 32);
    float inv = 1.f / sum;
#pragma unroll
    for (int i = 0; i < 8; ++i) p[i] *= inv;

    // V phase (unchanged pattern): lane accumulates output dims 4*lane..+3
    // (head lane>>3). p(a, h') lives in lanes {hi=a&1, h=h', any jj}.
    float acc0 = 0.f, acc1 = 0.f, acc2 = 0.f, acc3 = 0.f;
    const int hsel = (lane >> 3) << 2;       // h' * 4
#pragma unroll
    for (int a = 0; a < 16; ++a) {
        int row = rowbase + (imy + (a >> 2) - 1) * Ww + imx + (a & 3) - 1;
        uint2 vw = *(const uint2*)(v + (size_t)row * 256 + 4 * lane);
        float pa = __shfl(p[a >> 1], ((a & 1) << 5) + hsel);
        acc0 += pa * bflo(vw.x); acc1 += pa * bfhi(vw.x);
        acc2 += pa * bflo(vw.y); acc3 += pa * bfhi(vw.y);
    }
    uint2 o;
    o.x = pack2(acc0, acc1);
    o.y = pack2(acc2, acc3);
    *(uint2*)(ao + (size_t)pos * 256 + 4 * lane) = o;
}

// ---------------------------------------------------------------------------
// Output projection: out = ao(bf16) @ Wp, fp32 out; both operands staged via
// global_load_lds width=16.
// ---------------------------------------------------------------------------
__global__ __launch_bounds__(256) void gemm_proj(const u16* __restrict__ Ab,
                                                 const u16* __restrict__ Btg,
                                                 float* __restrict__ Cf)
{
    __shared__ __align__(16) char smem[32768];
    u16* sA = (u16*)smem;
    u16* sB = (u16*)(smem + 8192);

    const int t    = threadIdx.x;
    const int lane = t & 63;
    const int wv   = t >> 6;
    const int wm   = wv & 1;
    const int wn   = wv >> 1;
    const int m0   = blockIdx.y * 128;
    const int n0   = blockIdx.x * 128;

    const int r0  = t >> 2;
    const int kc0 = (t & 3) * 8;

    const int col  = lane & 15;
    const int quad = lane >> 4;

    f32x4 acc[4][4];
#pragma unroll
    for (int i = 0; i < 4; ++i)
#pragma unroll
        for (int j = 0; j < 4; ++j)
            acc[i][j] = (f32x4){0.f, 0.f, 0.f, 0.f};

    const u16* Bbase = Btg + (size_t)n0 * 256;
    char* ldsA0 = smem + wv * 1024;
    char* ldsA1 = smem + 4096 + wv * 1024;
    char* ldsB0 = smem + 8192 + wv * 1024;
    char* ldsB1 = smem + 8192 + 4096 + wv * 1024;

    for (int k0 = 0; k0 < 256; k0 += 32) {
        __syncthreads();
        gload16(Ab    + (size_t)(m0 + r0)      * 256 + k0 + kc0, ldsA0);
        gload16(Ab    + (size_t)(m0 + 64 + r0) * 256 + k0 + kc0, ldsA1);
        gload16(Bbase + (size_t)r0             * 256 + k0 + kc0, ldsB0);
        gload16(Bbase + (size_t)(64 + r0)      * 256 + k0 + kc0, ldsB1);
        __syncthreads();

        bf16x8 af[4], bfr[4];
#pragma unroll
        for (int mt = 0; mt < 4; ++mt)
            af[mt] = *(const bf16x8*)(sA + (wm * 64 + mt * 16 + col) * 32 + quad * 8);
#pragma unroll
        for (int nt = 0; nt < 4; ++nt)
            bfr[nt] = *(const bf16x8*)(sB + (wn * 64 + nt * 16 + col) * 32 + quad * 8);

#pragma unroll
        for (int mt = 0; mt < 4; ++mt)
#pragma unroll
            for (int nt = 0; nt < 4; ++nt)
                acc[mt][nt] = __builtin_amdgcn_mfma_f32_16x16x32_bf16(af[mt], bfr[nt], acc[mt][nt], 0, 0, 0);
    }

    __syncthreads();
    float* sC = (float*)smem;         // 64 x 128 fp32 = 32 KB per pass
#pragma unroll
    for (int ph = 0; ph < 2; ++ph) {
        if (wm == ph) {
#pragma unroll
            for (int mt = 0; mt < 4; ++mt)
#pragma unroll
                for (int nt = 0; nt < 4; ++nt) {
                    const int rw = mt * 16 + quad * 4;
                    const int cl = wn * 64 + nt * 16 + col;
#pragma unroll
                    for (int rr = 0; rr < 4; ++rr)
                        sC[(rw + rr) * 128 + cl] = acc[mt][nt][rr];
                }
        }
        __syncthreads();
#pragma unroll
        for (int i = 0; i < 8; ++i) {
            int j   = i * 256 + t;
            int row = j >> 5;
            int off = (j & 31) * 4;
            *(float4*)(Cf + (size_t)(m0 + ph * 64 + row) * 256 + n0 + off) =
                *(const float4*)(sC + row * 128 + off);
        }
        __syncthreads();
    }
}

// ---------------------------------------------------------------------------
extern "C" void kernel_launch(void* const* d_in, const int* in_sizes, int n_in,
                              void* d_out, int out_size, void* d_ws, size_t ws_size,
                              hipStream_t stream)
{
    const float* x     = (const float*)d_in[0];
    const float* moff  = (const float*)d_in[1];
    const float* Wq    = (const float*)d_in[2];
    const float* Wk    = (const float*)d_in[3];
    const float* Wv    = (const float*)d_in[4];
    const float* Wproj = (const float*)d_in[5];
    float* out = (float*)d_out;

    const size_t NTOT = (size_t)Bb * Nn * DIMc;   // 5,242,880
    u16* ws    = (u16*)d_ws;
    u16* WtAll = ws;
    u16* q     = WtAll + 4 * 65536;
    u16* k     = q + NTOT;
    u16* v     = k + NTOT;
    u16* ao    = v + NTOT;

    prep_w<<<dim3(1024), dim3(256), 0, stream>>>(Wq, Wk, Wv, Wproj, WtAll);
    gemm_qkv<<<dim3(2, 160, 3), dim3(256), 0, stream>>>(x, WtAll, q, k, v);
    attn_kernel<<<dim3(NPOS / 4), dim3(256), 0, stream>>>(q, k, v, moff, ao);
    gemm_proj<<<dim3(2, 160, 1), dim3(256), 0, stream>>>(ao, WtAll + (size_t)3 * 65536, out);
}

// Round 7
// 149.907 us; speedup vs baseline: 1.0332x; 1.0332x over previous
//
#include <hip/hip_runtime.h>
#include <math.h>

// Problem constants
#define Bb   2
#define Hh   64
#define Ww   160
#define DIMc 256
#define Nn   (Hh * Ww)                 // 10240 positions per batch
#define NPOS (Bb * Nn)                 // 20480 total positions
#define SCALEf 0.17677669529663687f    // 32^-0.5

typedef unsigned short u16;
typedef unsigned int   u32;
typedef __bf16 bf16x8 __attribute__((ext_vector_type(8)));
typedef float  f32x4  __attribute__((ext_vector_type(4)));

// fp32 -> bf16 round-to-nearest-even
__device__ __forceinline__ u16 f2bf(float f) {
    u32 u = __float_as_uint(f);
    u += 0x7fffu + ((u >> 16) & 1u);
    return (u16)(u >> 16);
}
__device__ __forceinline__ u32 pack2(float lo, float hi) {
    return (u32)f2bf(lo) | ((u32)f2bf(hi) << 16);
}
// packed bf16 pair -> floats (exact)
__device__ __forceinline__ float bflo(u32 u) { return __uint_as_float(u << 16); }
__device__ __forceinline__ float bfhi(u32 u) { return __uint_as_float(u & 0xffff0000u); }

// async global(16B) -> LDS direct staging (wave-uniform base + lane*16)
__device__ __forceinline__ void gload16(const void* g, void* l) {
    __builtin_amdgcn_global_load_lds(
        (const __attribute__((address_space(1))) unsigned int*)g,
        (__attribute__((address_space(3))) unsigned int*)l,
        16, 0, 0);
}

// ---------------------------------------------------------------------------
// prep_w: weights -> transposed bf16. Wt[wsel][n][k] = W[wsel][k][n]. (R0)
// ---------------------------------------------------------------------------
__global__ __launch_bounds__(256) void prep_w(const float* __restrict__ Wq,
                                              const float* __restrict__ Wk,
                                              const float* __restrict__ Wv,
                                              const float* __restrict__ Wp,
                                              u16* __restrict__ WtAll)
{
    int id = blockIdx.x * 256 + threadIdx.x;     // 0 .. 262143
    int wsel = id >> 16;
    int rem  = id & 65535;
    int kk = rem >> 8, nn = rem & 255;
    const float* W = (wsel == 0) ? Wq : (wsel == 1) ? Wk : (wsel == 2) ? Wv : Wp;
    WtAll[(size_t)wsel * 65536 + nn * 256 + kk] = f2bf(W[kk * 256 + nn]);
}

// ---------------------------------------------------------------------------
// QKV GEMM (R0-proven): A fp32 loaded + packed bf16 in-reg, B bf16 via
// global_load_lds width=16. Natural output layout.
// ---------------------------------------------------------------------------
__global__ __launch_bounds__(256) void gemm_qkv(const float* __restrict__ x,
                                                const u16* __restrict__ WtAll,
                                                u16* __restrict__ q,
                                                u16* __restrict__ k,
                                                u16* __restrict__ v)
{
    __shared__ __align__(16) char smem[32768];
    u16* sA = (u16*)smem;             //  8 KB: 128 rows x 32 k
    u16* sB = (u16*)(smem + 8192);    //  8 KB: 128 cols x 32 k

    const int z = blockIdx.z;
    u16* Cb = (z == 0) ? q : (z == 1) ? k : v;
    const u16* Btg = WtAll + (size_t)z * 65536;

    const int t    = threadIdx.x;
    const int lane = t & 63;
    const int wv   = t >> 6;
    const int wm   = wv & 1;
    const int wn   = wv >> 1;
    const int m0   = blockIdx.y * 128;
    const int n0   = blockIdx.x * 128;

    const int r0  = t >> 2;
    const int kc0 = (t & 3) * 8;

    const int col  = lane & 15;
    const int quad = lane >> 4;

    f32x4 acc[4][4];
#pragma unroll
    for (int i = 0; i < 4; ++i)
#pragma unroll
        for (int j = 0; j < 4; ++j)
            acc[i][j] = (f32x4){0.f, 0.f, 0.f, 0.f};

    const u16* Bbase = Btg + (size_t)n0 * 256;
    char* ldsB0 = smem + 8192 + wv * 1024;
    char* ldsB1 = smem + 8192 + 4096 + wv * 1024;

    for (int k0 = 0; k0 < 256; k0 += 32) {
        const float* ap0 = x + (size_t)(m0 + r0) * 256 + k0 + kc0;
        const float* ap1 = x + (size_t)(m0 + 64 + r0) * 256 + k0 + kc0;
        float4 f0 = *(const float4*)ap0, f1 = *(const float4*)(ap0 + 4);
        float4 f2 = *(const float4*)ap1, f3 = *(const float4*)(ap1 + 4);
        uint4 a0, a1;
        a0.x = pack2(f0.x, f0.y); a0.y = pack2(f0.z, f0.w);
        a0.z = pack2(f1.x, f1.y); a0.w = pack2(f1.z, f1.w);
        a1.x = pack2(f2.x, f2.y); a1.y = pack2(f2.z, f2.w);
        a1.z = pack2(f3.x, f3.y); a1.w = pack2(f3.z, f3.w);

        __syncthreads();
        *(uint4*)(sA + r0 * 32 + kc0)        = a0;
        *(uint4*)(sA + (64 + r0) * 32 + kc0) = a1;
        gload16(Bbase + (size_t)r0        * 256 + k0 + kc0, ldsB0);
        gload16(Bbase + (size_t)(64 + r0) * 256 + k0 + kc0, ldsB1);
        __syncthreads();

        bf16x8 af[4], bfr[4];
#pragma unroll
        for (int mt = 0; mt < 4; ++mt)
            af[mt] = *(const bf16x8*)(sA + (wm * 64 + mt * 16 + col) * 32 + quad * 8);
#pragma unroll
        for (int nt = 0; nt < 4; ++nt)
            bfr[nt] = *(const bf16x8*)(sB + (wn * 64 + nt * 16 + col) * 32 + quad * 8);

#pragma unroll
        for (int mt = 0; mt < 4; ++mt)
#pragma unroll
            for (int nt = 0; nt < 4; ++nt)
                acc[mt][nt] = __builtin_amdgcn_mfma_f32_16x16x32_bf16(af[mt], bfr[nt], acc[mt][nt], 0, 0, 0);
    }

    __syncthreads();
    u16* sC = (u16*)smem;             // 128 x 128 bf16 = 32 KB
#pragma unroll
    for (int mt = 0; mt < 4; ++mt)
#pragma unroll
        for (int nt = 0; nt < 4; ++nt) {
            const int rw = wm * 64 + mt * 16 + quad * 4;
            const int cl = wn * 64 + nt * 16 + col;
#pragma unroll
            for (int rr = 0; rr < 4; ++rr)
                sC[(rw + rr) * 128 + cl] = f2bf(acc[mt][nt][rr]);
        }
    __syncthreads();
#pragma unroll
    for (int i = 0; i < 8; ++i) {
        int j   = i * 256 + t;
        int row = j >> 4;
        int off = (j & 15) * 8;
        *(uint4*)(Cb + (size_t)(m0 + row) * 256 + n0 + off) = *(const uint4*)(sC + row * 128 + off);
    }
}

// ---------------------------------------------------------------------------
// Attention: R0 lane mapping (h=lane&7, a0=lane>>3), but TWO positions per
// wave, fully interleaved. Per-position instruction semantics are identical
// to the R0 kernel (bitwise-same result); the second position's independent
// chains fill the VALU idle gaps (R6 counters: VALU 44%, HBM 34%, both idle
// -> latency-bound). Grid: NPOS/8 blocks x 4 waves x 2 positions.
// ---------------------------------------------------------------------------
__global__ __launch_bounds__(256) void attn_kernel(const u16* __restrict__ q,
                                                   const u16* __restrict__ k,
                                                   const u16* __restrict__ v,
                                                   const float* __restrict__ moff,
                                                   u16* __restrict__ ao)
{
    const int wv   = threadIdx.x >> 6;
    const int lane = threadIdx.x & 63;
    const int h    = lane & 7;
    const int a0   = lane >> 3;
    const int myh  = lane >> 3;

    int pos[2], rowbase[2];
    pos[0] = blockIdx.x * 8 + wv;
    pos[1] = pos[0] + 4;
#pragma unroll
    for (int P = 0; P < 2; ++P) rowbase[P] = (pos[P] >= Nn) ? Nn : 0;

    float fx[2], fy[2];
    int   imx[2], imy[2];
#pragma unroll
    for (int P = 0; P < 2; ++P) {
        float2 mo = *(const float2*)(moff + (size_t)pos[P] * 2);
        float ox = fminf(fmaxf(mo.x, 1.0f), (float)(Ww - 2) - 0.001f);
        float oy = fminf(fmaxf(mo.y, 1.0f), (float)(Hh - 2) - 0.001f);
        float mxf = floorf(ox), myf = floorf(oy);
        fx[P] = ox - mxf; fy[P] = oy - myf;
        imx[P] = (int)mxf; imy[P] = (int)myf;
    }

    uint4 q4[2][4];
#pragma unroll
    for (int P = 0; P < 2; ++P) {
        const uint4* qp = (const uint4*)(q + (size_t)pos[P] * 256 + h * 32);
#pragma unroll
        for (int jj = 0; jj < 4; ++jj) q4[P][jj] = qp[jj];
    }

    // K phase: 4 independent dot chains (2 positions x 2 window-halves)
    float s[2][2];
#pragma unroll
    for (int p = 0; p < 2; ++p) {
#pragma unroll
        for (int P = 0; P < 2; ++P) {
            int a   = a0 + 8 * p;
            int row = rowbase[P] + (imy[P] + (a >> 2) - 1) * Ww + imx[P] + (a & 3) - 1;
            const uint4* kp = (const uint4*)(k + (size_t)row * 256 + h * 32);
            float acc = 0.f;
#pragma unroll
            for (int jj = 0; jj < 4; ++jj) {
                uint4 kw = kp[jj];
                acc += bflo(q4[P][jj].x) * bflo(kw.x) + bfhi(q4[P][jj].x) * bfhi(kw.x)
                     + bflo(q4[P][jj].y) * bflo(kw.y) + bfhi(q4[P][jj].y) * bfhi(kw.y)
                     + bflo(q4[P][jj].z) * bflo(kw.z) + bfhi(q4[P][jj].z) * bfhi(kw.z)
                     + bflo(q4[P][jj].w) * bflo(kw.w) + bfhi(q4[P][jj].w) * bfhi(kw.w);
            }
            s[P][p] = acc * SCALEf;
        }
    }

    auto wc = [](int r, float f) { return r == 0 ? 1.f - f : (r == 3 ? f : 1.f); };

    // softmax (both positions' shuffle trees interleave)
    float m[2], e0[2], e1[2], sum[2];
#pragma unroll
    for (int P = 0; P < 2; ++P) m[P] = fmaxf(s[P][0], s[P][1]);
#pragma unroll
    for (int P = 0; P < 2; ++P) m[P] = fmaxf(m[P], __shfl_xor(m[P], 8));
#pragma unroll
    for (int P = 0; P < 2; ++P) m[P] = fmaxf(m[P], __shfl_xor(m[P], 16));
#pragma unroll
    for (int P = 0; P < 2; ++P) m[P] = fmaxf(m[P], __shfl_xor(m[P], 32));
#pragma unroll
    for (int P = 0; P < 2; ++P) {
        float bw0 = wc(a0 >> 2, fy[P]) * wc(a0 & 3, fx[P]);
        float bw1 = wc((a0 + 8) >> 2, fy[P]) * wc(a0 & 3, fx[P]);
        e0[P] = expf(s[P][0] - m[P]) * bw0;
        e1[P] = expf(s[P][1] - m[P]) * bw1;
        sum[P] = e0[P] + e1[P];
    }
#pragma unroll
    for (int P = 0; P < 2; ++P) sum[P] += __shfl_xor(sum[P], 8);
#pragma unroll
    for (int P = 0; P < 2; ++P) sum[P] += __shfl_xor(sum[P], 16);
#pragma unroll
    for (int P = 0; P < 2; ++P) sum[P] += __shfl_xor(sum[P], 32);

    float p0[2], p1[2];
#pragma unroll
    for (int P = 0; P < 2; ++P) {
        float inv = 1.f / sum[P];
        p0[P] = e0[P] * inv;
        p1[P] = e1[P] * inv;
    }

    // V phase: 32 independent loads, 8 accumulators
    float acc0[2] = {0.f, 0.f}, acc1[2] = {0.f, 0.f};
    float acc2[2] = {0.f, 0.f}, acc3[2] = {0.f, 0.f};
#pragma unroll
    for (int a = 0; a < 16; ++a) {
        int src = ((a & 7) << 3) | myh;
#pragma unroll
        for (int P = 0; P < 2; ++P) {
            int row = rowbase[P] + (imy[P] + (a >> 2) - 1) * Ww + imx[P] + (a & 3) - 1;
            uint2 vw = *(const uint2*)(v + (size_t)row * 256 + 4 * lane);
            float pa = __shfl(a < 8 ? p0[P] : p1[P], src);
            acc0[P] += pa * bflo(vw.x); acc1[P] += pa * bfhi(vw.x);
            acc2[P] += pa * bflo(vw.y); acc3[P] += pa * bfhi(vw.y);
        }
    }
#pragma unroll
    for (int P = 0; P < 2; ++P) {
        uint2 o;
        o.x = pack2(acc0[P], acc1[P]);
        o.y = pack2(acc2[P], acc3[P]);
        *(uint2*)(ao + (size_t)pos[P] * 256 + 4 * lane) = o;
    }
}

// ---------------------------------------------------------------------------
// Output projection: out = ao(bf16) @ Wp, fp32 out; both operands staged via
// global_load_lds width=16. (R0)
// ---------------------------------------------------------------------------
__global__ __launch_bounds__(256) void gemm_proj(const u16* __restrict__ Ab,
                                                 const u16* __restrict__ Btg,
                                                 float* __restrict__ Cf)
{
    __shared__ __align__(16) char smem[32768];
    u16* sA = (u16*)smem;
    u16* sB = (u16*)(smem + 8192);

    const int t    = threadIdx.x;
    const int lane = t & 63;
    const int wv   = t >> 6;
    const int wm   = wv & 1;
    const int wn   = wv >> 1;
    const int m0   = blockIdx.y * 128;
    const int n0   = blockIdx.x * 128;

    const int r0  = t >> 2;
    const int kc0 = (t & 3) * 8;

    const int col  = lane & 15;
    const int quad = lane >> 4;

    f32x4 acc[4][4];
#pragma unroll
    for (int i = 0; i < 4; ++i)
#pragma unroll
        for (int j = 0; j < 4; ++j)
            acc[i][j] = (f32x4){0.f, 0.f, 0.f, 0.f};

    const u16* Bbase = Btg + (size_t)n0 * 256;
    char* ldsA0 = smem + wv * 1024;
    char* ldsA1 = smem + 4096 + wv * 1024;
    char* ldsB0 = smem + 8192 + wv * 1024;
    char* ldsB1 = smem + 8192 + 4096 + wv * 1024;

    for (int k0 = 0; k0 < 256; k0 += 32) {
        __syncthreads();
        gload16(Ab    + (size_t)(m0 + r0)      * 256 + k0 + kc0, ldsA0);
        gload16(Ab    + (size_t)(m0 + 64 + r0) * 256 + k0 + kc0, ldsA1);
        gload16(Bbase + (size_t)r0             * 256 + k0 + kc0, ldsB0);
        gload16(Bbase + (size_t)(64 + r0)      * 256 + k0 + kc0, ldsB1);
        __syncthreads();

        bf16x8 af[4], bfr[4];
#pragma unroll
        for (int mt = 0; mt < 4; ++mt)
            af[mt] = *(const bf16x8*)(sA + (wm * 64 + mt * 16 + col) * 32 + quad * 8);
#pragma unroll
        for (int nt = 0; nt < 4; ++nt)
            bfr[nt] = *(const bf16x8*)(sB + (wn * 64 + nt * 16 + col) * 32 + quad * 8);

#pragma unroll
        for (int mt = 0; mt < 4; ++mt)
#pragma unroll
            for (int nt = 0; nt < 4; ++nt)
                acc[mt][nt] = __builtin_amdgcn_mfma_f32_16x16x32_bf16(af[mt], bfr[nt], acc[mt][nt], 0, 0, 0);
    }

    __syncthreads();
    float* sC = (float*)smem;         // 64 x 128 fp32 = 32 KB per pass
#pragma unroll
    for (int ph = 0; ph < 2; ++ph) {
        if (wm == ph) {
#pragma unroll
            for (int mt = 0; mt < 4; ++mt)
#pragma unroll
                for (int nt = 0; nt < 4; ++nt) {
                    const int rw = mt * 16 + quad * 4;
                    const int cl = wn * 64 + nt * 16 + col;
#pragma unroll
                    for (int rr = 0; rr < 4; ++rr)
                        sC[(rw + rr) * 128 + cl] = acc[mt][nt][rr];
                }
        }
        __syncthreads();
#pragma unroll
        for (int i = 0; i < 8; ++i) {
            int j   = i * 256 + t;
            int row = j >> 5;
            int off = (j & 31) * 4;
            *(float4*)(Cf + (size_t)(m0 + ph * 64 + row) * 256 + n0 + off) =
                *(const float4*)(sC + row * 128 + off);
        }
        __syncthreads();
    }
}

// ---------------------------------------------------------------------------
extern "C" void kernel_launch(void* const* d_in, const int* in_sizes, int n_in,
                              void* d_out, int out_size, void* d_ws, size_t ws_size,
                              hipStream_t stream)
{
    const float* x     = (const float*)d_in[0];
    const float* moff  = (const float*)d_in[1];
    const float* Wq    = (const float*)d_in[2];
    const float* Wk    = (const float*)d_in[3];
    const float* Wv    = (const float*)d_in[4];
    const float* Wproj = (const float*)d_in[5];
    float* out = (float*)d_out;

    const size_t NTOT = (size_t)Bb * Nn * DIMc;   // 5,242,880
    u16* ws    = (u16*)d_ws;
    u16* WtAll = ws;
    u16* q     = WtAll + 4 * 65536;
    u16* k     = q + NTOT;
    u16* v     = k + NTOT;
    u16* ao    = v + NTOT;

    prep_w<<<dim3(1024), dim3(256), 0, stream>>>(Wq, Wk, Wv, Wproj, WtAll);
    gemm_qkv<<<dim3(2, 160, 3), dim3(256), 0, stream>>>(x, WtAll, q, k, v);
    attn_kernel<<<dim3(NPOS / 8), dim3(256), 0, stream>>>(q, k, v, moff, ao);
    gemm_proj<<<dim3(2, 160, 1), dim3(256), 0, stream>>>(ao, WtAll + (size_t)3 * 65536, out);
}

// Round 8
// 143.174 us; speedup vs baseline: 1.0818x; 1.0470x over previous
//
#include <hip/hip_runtime.h>
#include <math.h>

// Problem constants
#define Bb   2
#define Hh   64
#define Ww   160
#define DIMc 256
#define Nn   (Hh * Ww)                 // 10240 positions per batch
#define NPOS (Bb * Nn)                 // 20480 total positions
#define SCALEf 0.17677669529663687f    // 32^-0.5

typedef unsigned short u16;
typedef unsigned int   u32;
typedef __bf16 bf16x8 __attribute__((ext_vector_type(8)));
typedef float  f32x4  __attribute__((ext_vector_type(4)));

// fp32 -> bf16 round-to-nearest-even
__device__ __forceinline__ u16 f2bf(float f) {
    u32 u = __float_as_uint(f);
    u += 0x7fffu + ((u >> 16) & 1u);
    return (u16)(u >> 16);
}
__device__ __forceinline__ u32 pack2(float lo, float hi) {
    return (u32)f2bf(lo) | ((u32)f2bf(hi) << 16);
}
// packed bf16 pair -> floats (exact)
__device__ __forceinline__ float bflo(u32 u) { return __uint_as_float(u << 16); }
__device__ __forceinline__ float bfhi(u32 u) { return __uint_as_float(u & 0xffff0000u); }

// async global(16B) -> LDS direct staging (wave-uniform base + lane*16)
__device__ __forceinline__ void gload16(const void* g, void* l) {
    __builtin_amdgcn_global_load_lds(
        (const __attribute__((address_space(1))) unsigned int*)g,
        (__attribute__((address_space(3))) unsigned int*)l,
        16, 0, 0);
}

// ---------------------------------------------------------------------------
// prep_w: weights -> transposed bf16. Wt[wsel][n][k] = W[wsel][k][n]. (R0)
// ---------------------------------------------------------------------------
__global__ __launch_bounds__(256) void prep_w(const float* __restrict__ Wq,
                                              const float* __restrict__ Wk,
                                              const float* __restrict__ Wv,
                                              const float* __restrict__ Wp,
                                              u16* __restrict__ WtAll)
{
    int id = blockIdx.x * 256 + threadIdx.x;     // 0 .. 262143
    int wsel = id >> 16;
    int rem  = id & 65535;
    int kk = rem >> 8, nn = rem & 255;
    const float* W = (wsel == 0) ? Wq : (wsel == 1) ? Wk : (wsel == 2) ? Wv : Wp;
    WtAll[(size_t)wsel * 65536 + nn * 256 + kk] = f2bf(W[kk * 256 + nn]);
}

// ---------------------------------------------------------------------------
// QKV GEMM, retiled BM=64 x BN=256 (single n-block): the fp32 A (x, 21 MB,
// not L2-resident) is now read ONCE per z (63 MB total, was 126 MB across
// 2 n-blocks); the re-fetched operand is B (Wt, 0.5 MB, always XCD-L2-hit).
// 4 waves = 1m x 4n; per wave 4x4 grid of 16x16x32 MFMAs (acc unchanged).
// A fp32 loaded + packed bf16 in-reg (R0-proven); B via global_load_lds x4.
// Accumulation order per output element identical -> bitwise-same results.
// ---------------------------------------------------------------------------
__global__ __launch_bounds__(256) void gemm_qkv(const float* __restrict__ x,
                                                const u16* __restrict__ WtAll,
                                                u16* __restrict__ q,
                                                u16* __restrict__ k,
                                                u16* __restrict__ v)
{
    __shared__ __align__(16) char smem[32768];
    u16* sA = (u16*)smem;             //  4 KB: 64 rows x 32 k
    u16* sB = (u16*)(smem + 4096);    // 16 KB: 256 n x 32 k

    const int z = blockIdx.z;
    u16* Cb = (z == 0) ? q : (z == 1) ? k : v;
    const u16* Btg = WtAll + (size_t)z * 65536;

    const int t    = threadIdx.x;
    const int lane = t & 63;
    const int wv   = t >> 6;          // wave = n-quadrant (64 cols each)
    const int m0   = blockIdx.y * 64;

    const int r0  = t >> 2;           // 0..63
    const int kc0 = (t & 3) * 8;

    const int col  = lane & 15;
    const int quad = lane >> 4;

    f32x4 acc[4][4];
#pragma unroll
    for (int i = 0; i < 4; ++i)
#pragma unroll
        for (int j = 0; j < 4; ++j)
            acc[i][j] = (f32x4){0.f, 0.f, 0.f, 0.f};

    for (int k0 = 0; k0 < 256; k0 += 32) {
        // A: one row-segment of 8 fp32 per thread, packed to bf16 in-reg
        const float* ap = x + (size_t)(m0 + r0) * 256 + k0 + kc0;
        float4 f0 = *(const float4*)ap, f1 = *(const float4*)(ap + 4);
        uint4 a0;
        a0.x = pack2(f0.x, f0.y); a0.y = pack2(f0.z, f0.w);
        a0.z = pack2(f1.x, f1.y); a0.w = pack2(f1.z, f1.w);

        __syncthreads();   // prior iteration's ds_reads complete before overwrite
        *(uint4*)(sA + r0 * 32 + kc0) = a0;
        // B: 4 chunks/thread, n-rows r0, r0+64, r0+128, r0+192
        gload16(Btg + (size_t)r0         * 256 + k0 + kc0, smem + 4096  + wv * 1024);
        gload16(Btg + (size_t)(64 + r0)  * 256 + k0 + kc0, smem + 8192  + wv * 1024);
        gload16(Btg + (size_t)(128 + r0) * 256 + k0 + kc0, smem + 12288 + wv * 1024);
        gload16(Btg + (size_t)(192 + r0) * 256 + k0 + kc0, smem + 16384 + wv * 1024);
        __syncthreads();   // drains lgkmcnt (A ds_write) + vmcnt (B gload_lds)

        bf16x8 af[4], bfr[4];
#pragma unroll
        for (int mt = 0; mt < 4; ++mt)
            af[mt] = *(const bf16x8*)(sA + (mt * 16 + col) * 32 + quad * 8);
#pragma unroll
        for (int nt = 0; nt < 4; ++nt)
            bfr[nt] = *(const bf16x8*)(sB + (wv * 64 + nt * 16 + col) * 32 + quad * 8);

#pragma unroll
        for (int mt = 0; mt < 4; ++mt)
#pragma unroll
            for (int nt = 0; nt < 4; ++nt)
                acc[mt][nt] = __builtin_amdgcn_mfma_f32_16x16x32_bf16(af[mt], bfr[nt], acc[mt][nt], 0, 0, 0);
    }

    // Epilogue: C/D layout col=lane&15 (n), row=quad*4+reg (m). Stage via LDS.
    __syncthreads();
    u16* sC = (u16*)smem;             // 64 x 256 bf16 = 32 KB
#pragma unroll
    for (int mt = 0; mt < 4; ++mt)
#pragma unroll
        for (int nt = 0; nt < 4; ++nt) {
            const int rw = mt * 16 + quad * 4;
            const int cl = wv * 64 + nt * 16 + col;
#pragma unroll
            for (int rr = 0; rr < 4; ++rr)
                sC[(rw + rr) * 256 + cl] = f2bf(acc[mt][nt][rr]);
        }
    __syncthreads();
    // 64 rows x 256 cols x 2B = 2048 16B chunks; 8/thread; rows contiguous
#pragma unroll
    for (int i = 0; i < 8; ++i) {
        int j   = i * 256 + t;
        int row = j >> 5;
        int off = (j & 31) * 8;
        *(uint4*)(Cb + (size_t)(m0 + row) * 256 + off) = *(const uint4*)(sC + row * 256 + off);
    }
}

// ---------------------------------------------------------------------------
// Attention: ONE WAVE per position — exact R0-measured structure (best).
// ---------------------------------------------------------------------------
__global__ __launch_bounds__(256) void attn_kernel(const u16* __restrict__ q,
                                                   const u16* __restrict__ k,
                                                   const u16* __restrict__ v,
                                                   const float* __restrict__ moff,
                                                   u16* __restrict__ ao)
{
    const int wv   = threadIdx.x >> 6;
    const int lane = threadIdx.x & 63;
    const int pos  = blockIdx.x * 4 + wv;
    const int rowbase = (pos >= Nn) ? Nn : 0;

    float2 mo = *(const float2*)(moff + (size_t)pos * 2);
    float ox = fminf(fmaxf(mo.x, 1.0f), (float)(Ww - 2) - 0.001f);
    float oy = fminf(fmaxf(mo.y, 1.0f), (float)(Hh - 2) - 0.001f);
    float mxf = floorf(ox), myf = floorf(oy);
    float fx = ox - mxf, fy = oy - myf;
    int imx = (int)mxf, imy = (int)myf;

    const int h  = lane & 7;
    const int a0 = lane >> 3;

    uint4 q4[4];
    {
        const uint4* qp = (const uint4*)(q + (size_t)pos * 256 + h * 32);
#pragma unroll
        for (int jj = 0; jj < 4; ++jj) q4[jj] = qp[jj];
    }

    float s[2];
#pragma unroll
    for (int p = 0; p < 2; ++p) {
        int a   = a0 + 8 * p;
        int row = rowbase + (imy + (a >> 2) - 1) * Ww + imx + (a & 3) - 1;
        const uint4* kp = (const uint4*)(k + (size_t)row * 256 + h * 32);
        float acc = 0.f;
#pragma unroll
        for (int jj = 0; jj < 4; ++jj) {
            uint4 kw = kp[jj];
            acc += bflo(q4[jj].x) * bflo(kw.x) + bfhi(q4[jj].x) * bfhi(kw.x)
                 + bflo(q4[jj].y) * bflo(kw.y) + bfhi(q4[jj].y) * bfhi(kw.y)
                 + bflo(q4[jj].z) * bflo(kw.z) + bfhi(q4[jj].z) * bfhi(kw.z)
                 + bflo(q4[jj].w) * bflo(kw.w) + bfhi(q4[jj].w) * bfhi(kw.w);
        }
        s[p] = acc * SCALEf;
    }

    auto wc = [](int r, float f) { return r == 0 ? 1.f - f : (r == 3 ? f : 1.f); };
    float bw0 = wc(a0 >> 2, fy) * wc(a0 & 3, fx);
    float bw1 = wc((a0 + 8) >> 2, fy) * wc(a0 & 3, fx);

    float m = fmaxf(s[0], s[1]);
    m = fmaxf(m, __shfl_xor(m, 8));
    m = fmaxf(m, __shfl_xor(m, 16));
    m = fmaxf(m, __shfl_xor(m, 32));
    float e0 = expf(s[0] - m) * bw0;
    float e1 = expf(s[1] - m) * bw1;
    float sum = e0 + e1;
    sum += __shfl_xor(sum, 8);
    sum += __shfl_xor(sum, 16);
    sum += __shfl_xor(sum, 32);
    float inv = 1.f / sum;
    float p0 = e0 * inv, p1 = e1 * inv;

    float acc0 = 0.f, acc1 = 0.f, acc2 = 0.f, acc3 = 0.f;
    const int myh = lane >> 3;
#pragma unroll
    for (int a = 0; a < 16; ++a) {
        int row = rowbase + (imy + (a >> 2) - 1) * Ww + imx + (a & 3) - 1;
        uint2 vw = *(const uint2*)(v + (size_t)row * 256 + 4 * lane);
        int src = ((a & 7) << 3) | myh;
        float pa = __shfl(a < 8 ? p0 : p1, src);
        acc0 += pa * bflo(vw.x); acc1 += pa * bfhi(vw.x);
        acc2 += pa * bflo(vw.y); acc3 += pa * bfhi(vw.y);
    }
    uint2 o;
    o.x = pack2(acc0, acc1);
    o.y = pack2(acc2, acc3);
    *(uint2*)(ao + (size_t)pos * 256 + 4 * lane) = o;
}

// ---------------------------------------------------------------------------
// Output projection, retiled BM=64 x BN=256: ao read once (10.5 MB, was 21);
// Wp re-fetched from L2. A (bf16) via 1 gload16/thread, B via 4.
// fp32 out staged through LDS in 2 phases of 32 rows.
// ---------------------------------------------------------------------------
__global__ __launch_bounds__(256) void gemm_proj(const u16* __restrict__ Ab,
                                                 const u16* __restrict__ Btg,
                                                 float* __restrict__ Cf)
{
    __shared__ __align__(16) char smem[32768];
    u16* sA = (u16*)smem;             //  4 KB: 64 rows x 32 k
    u16* sB = (u16*)(smem + 4096);    // 16 KB: 256 n x 32 k

    const int t    = threadIdx.x;
    const int lane = t & 63;
    const int wv   = t >> 6;
    const int m0   = blockIdx.y * 64;

    const int r0  = t >> 2;
    const int kc0 = (t & 3) * 8;

    const int col  = lane & 15;
    const int quad = lane >> 4;

    f32x4 acc[4][4];
#pragma unroll
    for (int i = 0; i < 4; ++i)
#pragma unroll
        for (int j = 0; j < 4; ++j)
            acc[i][j] = (f32x4){0.f, 0.f, 0.f, 0.f};

    for (int k0 = 0; k0 < 256; k0 += 32) {
        __syncthreads();
        gload16(Ab  + (size_t)(m0 + r0)  * 256 + k0 + kc0, smem          + wv * 1024);
        gload16(Btg + (size_t)r0         * 256 + k0 + kc0, smem + 4096   + wv * 1024);
        gload16(Btg + (size_t)(64 + r0)  * 256 + k0 + kc0, smem + 8192   + wv * 1024);
        gload16(Btg + (size_t)(128 + r0) * 256 + k0 + kc0, smem + 12288  + wv * 1024);
        gload16(Btg + (size_t)(192 + r0) * 256 + k0 + kc0, smem + 16384  + wv * 1024);
        __syncthreads();

        bf16x8 af[4], bfr[4];
#pragma unroll
        for (int mt = 0; mt < 4; ++mt)
            af[mt] = *(const bf16x8*)(sA + (mt * 16 + col) * 32 + quad * 8);
#pragma unroll
        for (int nt = 0; nt < 4; ++nt)
            bfr[nt] = *(const bf16x8*)(sB + (wv * 64 + nt * 16 + col) * 32 + quad * 8);

#pragma unroll
        for (int mt = 0; mt < 4; ++mt)
#pragma unroll
            for (int nt = 0; nt < 4; ++nt)
                acc[mt][nt] = __builtin_amdgcn_mfma_f32_16x16x32_bf16(af[mt], bfr[nt], acc[mt][nt], 0, 0, 0);
    }

    __syncthreads();
    float* sC = (float*)smem;         // 32 rows x 256 f32 = 32 KB per phase
#pragma unroll
    for (int ph = 0; ph < 2; ++ph) {
#pragma unroll
        for (int lm = 0; lm < 2; ++lm) {
            const int mt = 2 * ph + lm;
#pragma unroll
            for (int nt = 0; nt < 4; ++nt) {
                const int rw = lm * 16 + quad * 4;
                const int cl = wv * 64 + nt * 16 + col;
#pragma unroll
                for (int rr = 0; rr < 4; ++rr)
                    sC[(rw + rr) * 256 + cl] = acc[mt][nt][rr];
            }
        }
        __syncthreads();
        // 32 rows x 256 f32 = 2048 16B chunks; 8/thread; rows contiguous 1KB
#pragma unroll
        for (int i = 0; i < 8; ++i) {
            int j   = i * 256 + t;
            int row = j >> 6;
            int off = (j & 63) * 4;
            *(float4*)(Cf + (size_t)(m0 + ph * 32 + row) * 256 + off) =
                *(const float4*)(sC + row * 256 + off);
        }
        __syncthreads();
    }
}

// ---------------------------------------------------------------------------
extern "C" void kernel_launch(void* const* d_in, const int* in_sizes, int n_in,
                              void* d_out, int out_size, void* d_ws, size_t ws_size,
                              hipStream_t stream)
{
    const float* x     = (const float*)d_in[0];
    const float* moff  = (const float*)d_in[1];
    const float* Wq    = (const float*)d_in[2];
    const float* Wk    = (const float*)d_in[3];
    const float* Wv    = (const float*)d_in[4];
    const float* Wproj = (const float*)d_in[5];
    float* out = (float*)d_out;

    const size_t NTOT = (size_t)Bb * Nn * DIMc;   // 5,242,880
    u16* ws    = (u16*)d_ws;
    u16* WtAll = ws;
    u16* q     = WtAll + 4 * 65536;
    u16* k     = q + NTOT;
    u16* v     = k + NTOT;
    u16* ao    = v + NTOT;

    prep_w<<<dim3(1024), dim3(256), 0, stream>>>(Wq, Wk, Wv, Wproj, WtAll);
    gemm_qkv<<<dim3(1, 320, 3), dim3(256), 0, stream>>>(x, WtAll, q, k, v);
    attn_kernel<<<dim3(NPOS / 4), dim3(256), 0, stream>>>(q, k, v, moff, ao);
    gemm_proj<<<dim3(1, 320), dim3(256), 0, stream>>>(ao, WtAll + (size_t)3 * 65536, out);
}